// Round 1
// baseline (969.155 us; speedup 1.0000x reference)
//
#include <hip/hip_runtime.h>

#define D 128
#define NL 3

static inline size_t align256(size_t x){ return (x + 255) & ~(size_t)255; }

// ---------------- embedding gather: x[n] = z_table[z[n]] ----------------
__global__ __launch_bounds__(256) void k_embed(const int* __restrict__ z, const float* __restrict__ zt,
                                               float* __restrict__ x, int N){
    int i = blockIdx.x * blockDim.x + threadIdx.x;   // over N*32 float4s
    int n = i >> 5, q = i & 31;
    if (n >= N) return;
    float4 v = *(const float4*)&zt[(size_t)z[n] * D + q * 4];
    *(float4*)&x[(size_t)n * D + q * 4] = v;
}

// ---------------- degree count ----------------
__global__ __launch_bounds__(256) void k_deg(const int* __restrict__ dst, int* __restrict__ deg, int E){
    int e = blockIdx.x * blockDim.x + threadIdx.x;
    if (e < E) atomicAdd(&deg[dst[e]], 1);
}

__global__ __launch_bounds__(256) void k_invdeg(const int* __restrict__ deg, float* __restrict__ invdeg, int N){
    int n = blockIdx.x * blockDim.x + threadIdx.x;
    if (n < N) invdeg[n] = 1.0f / (float)max(deg[n], 1);
}

// ---------------- exclusive scan of deg -> offs (3-kernel) ----------------
#define SCAN_B 512
__global__ __launch_bounds__(SCAN_B) void k_scan1(const int* __restrict__ deg, int* __restrict__ bsum, int N){
    __shared__ int s[SCAN_B];
    int i = blockIdx.x * SCAN_B + threadIdx.x;
    s[threadIdx.x] = (i < N) ? deg[i] : 0;
    __syncthreads();
    for (int st = SCAN_B / 2; st > 0; st >>= 1){
        if (threadIdx.x < st) s[threadIdx.x] += s[threadIdx.x + st];
        __syncthreads();
    }
    if (threadIdx.x == 0) bsum[blockIdx.x] = s[0];
}

__global__ __launch_bounds__(SCAN_B) void k_scan2(int* __restrict__ bsum, int nb){
    __shared__ int s[SCAN_B];
    int t = threadIdx.x;
    int v = (t < nb) ? bsum[t] : 0;
    s[t] = v; __syncthreads();
    for (int st = 1; st < SCAN_B; st <<= 1){
        int u = (t >= st) ? s[t - st] : 0;
        __syncthreads();
        s[t] += u;
        __syncthreads();
    }
    if (t < nb) bsum[t] = s[t] - v;   // exclusive
}

__global__ __launch_bounds__(SCAN_B) void k_scan3(const int* __restrict__ deg, const int* __restrict__ bsum,
                                                  int* __restrict__ offs, int N, int E){
    __shared__ int s[SCAN_B];
    int i = blockIdx.x * SCAN_B + threadIdx.x;
    int v = (i < N) ? deg[i] : 0;
    s[threadIdx.x] = v; __syncthreads();
    for (int st = 1; st < SCAN_B; st <<= 1){
        int u = (threadIdx.x >= st) ? s[threadIdx.x - st] : 0;
        __syncthreads();
        s[threadIdx.x] += u;
        __syncthreads();
    }
    if (i < N) offs[i] = s[threadIdx.x] - v + bsum[blockIdx.x];
    if (blockIdx.x == 0 && threadIdx.x == 0) offs[N] = E;
}

// ---------------- CSR fill (src list grouped by dst) ----------------
__global__ __launch_bounds__(256) void k_fill(const int* __restrict__ src, const int* __restrict__ dst,
                                              int* __restrict__ cursor, int* __restrict__ ebuf, int E){
    int e = blockIdx.x * blockDim.x + threadIdx.x;
    if (e < E){ int p = atomicAdd(&cursor[dst[e]], 1); ebuf[p] = src[e]; }
}

// ---------------- segment starts ----------------
__global__ __launch_bounds__(256) void k_centers(const int* __restrict__ batch, int* __restrict__ centers, int N){
    int n = blockIdx.x * blockDim.x + threadIdx.x;
    if (n < N && (n == 0 || batch[n] != batch[n - 1])) centers[batch[n]] = n;
}

// ---------------- weight prep: Wcomb[l][k][d], W1T[k][d] ----------------
__global__ __launch_bounds__(256) void k_prepW(const float* __restrict__ Wl, const float* __restrict__ Wr,
                                               float* __restrict__ Wcomb, const float* __restrict__ W1,
                                               float* __restrict__ W1T){
    int i = blockIdx.x * blockDim.x + threadIdx.x;
    if (i < NL * 2 * D * D){
        int l = i / (2 * D * D); int r = i % (2 * D * D); int k = r / D; int d = r % D;
        Wcomb[i] = (k < D) ? Wl[(size_t)l * D * D + d * D + k]
                           : Wr[(size_t)l * D * D + d * D + (k - D)];
    }
    if (i < D * D){ int k = i / D, d = i % D; W1T[i] = W1[d * D + k]; }
}

// ---------------- mean aggregation (gather over CSR) ----------------
// one 32-lane half-wave per node, float4 per lane (32*16B = 512B row)
__global__ __launch_bounds__(256) void k_agg(const float* __restrict__ x, const int* __restrict__ ebuf,
                                             const int* __restrict__ offs, const float* __restrict__ invdeg,
                                             float* __restrict__ agg, int N){
    int node = blockIdx.x * 8 + (threadIdx.x >> 5);
    if (node >= N) return;
    int lane = threadIdx.x & 31;
    int s = offs[node], e = offs[node + 1];
    const float4* x4 = (const float4*)x;
    float4 acc = make_float4(0.f, 0.f, 0.f, 0.f);
    for (int i = s; i < e; ++i){
        int nb = ebuf[i];
        float4 v = x4[(size_t)nb * 32 + lane];
        acc.x += v.x; acc.y += v.y; acc.z += v.z; acc.w += v.w;
    }
    float sc = invdeg[node];
    acc.x *= sc; acc.y *= sc; acc.z *= sc; acc.w *= sc;
    ((float4*)agg)[(size_t)node * 32 + lane] = acc;
}

// ---------------- fused dense: Out = [agg | x] @ Wcomb + bias, optional relu ----------------
// block 256, tile 64 rows x 128 cols, 8 rows x 4 cols per thread
template<bool RELU>
__global__ __launch_bounds__(256) void k_dense(const float* __restrict__ Ag, const float* __restrict__ X,
                                               const float* __restrict__ Wc, const float* __restrict__ bias,
                                               float* __restrict__ Out, int N){
    __shared__ float Alds[64][33];
    const int tx = threadIdx.x & 31;   // col group: cols tx*4..tx*4+3
    const int ty = threadIdx.x >> 5;   // row group: rows ty*8..ty*8+7
    const int base = blockIdx.x * 64;
    float acc[8][4];
    #pragma unroll
    for (int r = 0; r < 8; ++r){ acc[r][0] = acc[r][1] = acc[r][2] = acc[r][3] = 0.f; }

    for (int kc = 0; kc < 8; ++kc){
        const float* S = (kc < 4) ? Ag : X;
        const int ko = (kc & 3) * 32;
        __syncthreads();
        #pragma unroll
        for (int j = 0; j < 2; ++j){
            int f = threadIdx.x + j * 256;     // 0..511 -> 64 rows x 8 float4
            int row = f >> 3, kq = f & 7;
            int gr = base + row;
            float4 v = make_float4(0.f, 0.f, 0.f, 0.f);
            if (gr < N) v = *(const float4*)&S[(size_t)gr * D + ko + kq * 4];
            Alds[row][kq * 4 + 0] = v.x; Alds[row][kq * 4 + 1] = v.y;
            Alds[row][kq * 4 + 2] = v.z; Alds[row][kq * 4 + 3] = v.w;
        }
        __syncthreads();
        #pragma unroll
        for (int kk = 0; kk < 32; ++kk){
            const int k = kc * 32 + kk;
            const float4 wv = *(const float4*)&Wc[(size_t)k * D + tx * 4];
            #pragma unroll
            for (int r = 0; r < 8; ++r){
                const float a = Alds[ty * 8 + r][kk];
                acc[r][0] = fmaf(a, wv.x, acc[r][0]);
                acc[r][1] = fmaf(a, wv.y, acc[r][1]);
                acc[r][2] = fmaf(a, wv.z, acc[r][2]);
                acc[r][3] = fmaf(a, wv.w, acc[r][3]);
            }
        }
    }
    const float4 bv = *(const float4*)&bias[tx * 4];
    #pragma unroll
    for (int r = 0; r < 8; ++r){
        int row = base + ty * 8 + r;
        if (row < N){
            float4 o;
            o.x = acc[r][0] + bv.x; o.y = acc[r][1] + bv.y;
            o.z = acc[r][2] + bv.z; o.w = acc[r][3] + bv.w;
            if (RELU){
                o.x = fmaxf(o.x, 0.f); o.y = fmaxf(o.y, 0.f);
                o.z = fmaxf(o.z, 0.f); o.w = fmaxf(o.w, 0.f);
            }
            *(float4*)&Out[(size_t)row * D + tx * 4] = o;
        }
    }
}

// ---------------- head: out[g] = W2 @ relu(W1 @ (x[c]*x[c+1]) + b1) + b2 ----------------
__global__ __launch_bounds__(128) void k_head(const float* __restrict__ x, const int* __restrict__ centers,
                                              const float* __restrict__ W1T, const float* __restrict__ b1,
                                              const float* __restrict__ W2, const float* __restrict__ b2,
                                              float* __restrict__ out){
    __shared__ float hs[D];
    __shared__ float red[D];
    int g = blockIdx.x; int d = threadIdx.x;
    int c = centers[g];
    hs[d] = x[(size_t)c * D + d] * x[(size_t)(c + 1) * D + d];
    __syncthreads();
    float acc = b1[d];
    #pragma unroll 8
    for (int k = 0; k < D; ++k) acc = fmaf(hs[k], W1T[k * D + d], acc);
    acc = fmaxf(acc, 0.f);
    red[d] = acc * W2[d];
    __syncthreads();
    for (int st = 64; st > 0; st >>= 1){
        if (d < st) red[d] += red[d + st];
        __syncthreads();
    }
    if (d == 0) out[g] = red[0] + b2[0];
}

extern "C" void kernel_launch(void* const* d_in, const int* in_sizes, int n_in,
                              void* d_out, int out_size, void* d_ws, size_t ws_size,
                              hipStream_t stream){
    const int*   z     = (const int*)  d_in[0];
    const int*   eidx  = (const int*)  d_in[1];
    const int*   batch = (const int*)  d_in[2];
    const float* zt    = (const float*)d_in[3];
    const float* Wl    = (const float*)d_in[4];
    const float* bl    = (const float*)d_in[5];
    const float* Wr    = (const float*)d_in[6];
    const float* W1    = (const float*)d_in[7];
    const float* b1    = (const float*)d_in[8];
    const float* W2    = (const float*)d_in[9];
    const float* b2    = (const float*)d_in[10];
    float* out = (float*)d_out;

    const int N = in_sizes[0];
    const int E = in_sizes[1] / 2;
    const int G = out_size;
    const int* src  = eidx;
    const int* dstp = eidx + E;

    char* p = (char*)d_ws;
    auto alloc = [&](size_t bytes){ char* r = p; p += align256(bytes); return r; };
    float* xa      = (float*)alloc((size_t)N * D * 4);
    float* xb      = (float*)alloc((size_t)N * D * 4);
    float* agg     = (float*)alloc((size_t)N * D * 4);
    int*   deg     = (int*)  alloc((size_t)N * 4);
    float* invdeg  = (float*)alloc((size_t)N * 4);
    int*   offs    = (int*)  alloc((size_t)(N + 1) * 4);
    int*   cursor  = (int*)  alloc((size_t)N * 4);
    int*   ebuf    = (int*)  alloc((size_t)E * 4);
    int*   centers = (int*)  alloc((size_t)G * 4);
    int*   bsum    = (int*)  alloc((size_t)1024 * 4);
    float* Wcomb   = (float*)alloc((size_t)NL * 2 * D * D * 4);
    float* W1T     = (float*)alloc((size_t)D * D * 4);
    (void)ws_size; (void)n_in;

    hipMemsetAsync(deg, 0, (size_t)N * 4, stream);
    k_embed<<<(N * 32 + 255) / 256, 256, 0, stream>>>(z, zt, xa, N);
    k_deg<<<(E + 255) / 256, 256, 0, stream>>>(dstp, deg, E);
    k_invdeg<<<(N + 255) / 256, 256, 0, stream>>>(deg, invdeg, N);
    int nb1 = (N + SCAN_B - 1) / SCAN_B;
    k_scan1<<<nb1, SCAN_B, 0, stream>>>(deg, bsum, N);
    k_scan2<<<1, SCAN_B, 0, stream>>>(bsum, nb1);
    k_scan3<<<nb1, SCAN_B, 0, stream>>>(deg, bsum, offs, N, E);
    hipMemcpyAsync(cursor, offs, (size_t)N * 4, hipMemcpyDeviceToDevice, stream);
    k_fill<<<(E + 255) / 256, 256, 0, stream>>>(src, dstp, cursor, ebuf, E);
    k_centers<<<(N + 255) / 256, 256, 0, stream>>>(batch, centers, N);
    k_prepW<<<(NL * 2 * D * D + 255) / 256, 256, 0, stream>>>(Wl, Wr, Wcomb, W1, W1T);

    float* xc = xa; float* xn = xb;
    for (int l = 0; l < NL; ++l){
        k_agg<<<(N + 7) / 8, 256, 0, stream>>>(xc, ebuf, offs, invdeg, agg, N);
        if (l < NL - 1)
            k_dense<true ><<<(N + 63) / 64, 256, 0, stream>>>(agg, xc, Wcomb + (size_t)l * 2 * D * D, bl + l * D, xn, N);
        else
            k_dense<false><<<(N + 63) / 64, 256, 0, stream>>>(agg, xc, Wcomb + (size_t)l * 2 * D * D, bl + l * D, xn, N);
        float* t = xc; xc = xn; xn = t;
    }
    k_head<<<G, 128, 0, stream>>>(xc, centers, W1T, b1, W2, b2, out);
}